// Round 20
// baseline (13.421 us; speedup 1.0000x reference)
//
#include <hip/hip_runtime.h>

#define BB 256
#define PP 64
#define LL 16
#define DD 64
#define IMGF 512

typedef float v4f __attribute__((ext_vector_type(4)));

// ---- fast cross-lane primitives ----
__device__ __forceinline__ float dxor1(float v) {
    return __int_as_float(__builtin_amdgcn_mov_dpp(__float_as_int(v), 0xB1, 0xF, 0xF, true));
}
__device__ __forceinline__ float dxor2(float v) {
    return __int_as_float(__builtin_amdgcn_mov_dpp(__float_as_int(v), 0x4E, 0xF, 0xF, true));
}
__device__ __forceinline__ float sxor4(float v) {
    return __int_as_float(__builtin_amdgcn_ds_swizzle(__float_as_int(v), 0x101F));
}
__device__ __forceinline__ float sxor8(float v) {
    return __int_as_float(__builtin_amdgcn_ds_swizzle(__float_as_int(v), 0x201F));
}
__device__ __forceinline__ float sxor16(float v) {
    return __int_as_float(__builtin_amdgcn_ds_swizzle(__float_as_int(v), 0x401F));
}
// broadcast from lane ((lane32 & 0x10) | srcl) within each 32-lane half
#define SWZB(x, srcl) __builtin_amdgcn_ds_swizzle((x), (((srcl) << 5) | 0x10))

__device__ __forceinline__ float wred_sum(float v) {
    v += __shfl_xor(v, 32, 64);
    v += sxor16(v);
    v += sxor8(v);
    v += sxor4(v);
    v += dxor2(v);
    v += dxor1(v);
    return v;
}
__device__ __forceinline__ float wred_max(float v) {
    v = fmaxf(v, __shfl_xor(v, 32, 64));
    v = fmaxf(v, sxor16(v));
    v = fmaxf(v, sxor8(v));
    v = fmaxf(v, sxor4(v));
    v = fmaxf(v, dxor2(v));
    v = fmaxf(v, dxor1(v));
    return v;
}
__device__ __forceinline__ float gred_sum16(float v) {
    v += dxor1(v);
    v += dxor2(v);
    v += sxor4(v);
    v += sxor8(v);
    return v;
}

// dot of two 4-vectors via packed ops + horizontal add
__device__ __forceinline__ float dot4v(v4f a, v4f b) {
    v4f m = a * b;
    return (m.x + m.y) + (m.z + m.w);
}

// 1/max(sqrt(n),1e-12) ~= rsqrt(max(n,1e-24)): single v_rsq_f32, ~2ulp.
__device__ __forceinline__ float rnorm_fast(float n) {
    return rsqrtf(fmaxf(n, 1e-24f));
}

// R18/R19 structure + whole-vector (ext_vector) arithmetic so the backend
// emits packed v_pk_{fma,mul,add}_f32 on the big FMA chains; /3 folded into
// the i*n scales. Schedule, barriers, reductions unchanged.
__launch_bounds__(1024, 1)
__global__ void k_fused(const int* __restrict__ qry_id, const int* __restrict__ res_id,
                        const int* __restrict__ path, const int* __restrict__ mask,
                        const float* __restrict__ img, const float* __restrict__ Ww,
                        const float* __restrict__ Wb,
                        const float* __restrict__ meta,
                        const float* __restrict__ hw, const float* __restrict__ hb,
                        const float* __restrict__ p1w, const float* __restrict__ p1b,
                        const float* __restrict__ p2w, const float* __restrict__ p2b,
                        float* __restrict__ out) {
    __shared__ float fq[IMGF], fr[IMGF];     // staged image feature rows
    __shared__ float pq_row[DD], pr_row[DD]; // GEMV row dots (pre-norm)
    __shared__ float qf[DD], rf[DD];         // normalized features
    __shared__ float pr_sh[PP][DD];          // path_res
    __shared__ float weight_sh[PP];
    __shared__ float wsh[PP];

    int b = blockIdx.x;
    int tid = threadIdx.x;
    int lane = tid & 63;
    int wv = tid >> 6;        // 0..15
    int g = lane >> 4;        // 16-lane group in wave: 0..3
    int j = lane & 15;        // lane within group
    int p = wv * 4 + g;       // this group's path index

    // ---- load this group's path indices+mask (coalesced, 1 int/lane) ----
    int pj = path[(b * PP + p) * LL + j];
    int mj = mask[(b * PP + p) * LL + j];
    int boff = (mj ? pj : 0) << 8;           // pre-masked byte offset (row j)

    // ---- stage the two gathered image-feature rows (coalesced) ----
    {
        int qid = qry_id[b], rid = res_id[b];
        if (tid < IMGF) fq[tid] = img[(long long)qid * IMGF + tid];
        else            fr[tid - IMGF] = img[(long long)rid * IMGF + (tid - IMGF)];
    }
    __syncthreads();                         // bar1

    // ---- GEMV: group (wv,g) owns output row p; contiguous float4 striding ----
    {
        const v4f* wr  = (const v4f*)(Ww + p * IMGF);
        const v4f* q4p = (const v4f*)fq;
        const v4f* r4p = (const v4f*)fr;
        float aq = 0.f, ar = 0.f;
#pragma unroll
        for (int i = 0; i < 8; ++i) {
            v4f w4 = wr[i * 16 + j];               // group: 256B contiguous
            aq += dot4v(w4, q4p[i * 16 + j]);
            ar += dot4v(w4, r4p[i * 16 + j]);
        }
        aq = gred_sum16(aq);
        ar = gred_sum16(ar);
        if (j == 0) { pq_row[p] = aq; pr_row[p] = ar; }
    }
    __syncthreads();                         // bar2
    if (wv < 2) {                      // finish norms while others issue gathers
        float acc = Wb[lane] + (wv ? pr_row[lane] : pq_row[lane]);
        float n = wred_sum(acc * acc);
        float val = acc * rnorm_fast(n);
        (wv ? rf : qf)[lane] = val;
    }

    // ---- path: issue all 16 gathers via swizzle-broadcast byte offsets ----
    const char* mbase = (const char*)meta + (j << 4);
    v4f v[16];
#define GATHER(l) v[l] = *(const v4f*)(mbase + SWZB(boff, l))
    GATHER(0);  GATHER(1);  GATHER(2);  GATHER(3);
    GATHER(4);  GATHER(5);  GATHER(6);  GATHER(7);
    GATHER(8);  GATHER(9);  GATHER(10); GATHER(11);
    GATHER(12); GATHER(13); GATHER(14); GATHER(15);
#undef GATHER

    float ss[16];
#pragma unroll
    for (int l = 0; l < LL; ++l) ss[l] = dot4v(v[l], v[l]);

    // ---- reduce-scatter across the 16-lane group: lane j <- total of row j ----
    float s8[8];
    {
        bool hi = (lane & 8) != 0;
#pragma unroll
        for (int i = 0; i < 8; ++i) {
            float snd = hi ? ss[i] : ss[i + 8];
            float kp  = hi ? ss[i + 8] : ss[i];
            s8[i] = kp + sxor8(snd);
        }
    }
    float s4[4];
    {
        bool hi = (lane & 4) != 0;
#pragma unroll
        for (int i = 0; i < 4; ++i) {
            float snd = hi ? s8[i] : s8[i + 4];
            float kp  = hi ? s8[i + 4] : s8[i];
            s4[i] = kp + sxor4(snd);
        }
    }
    float s2[2];
    {
        bool hi = (lane & 2) != 0;
#pragma unroll
        for (int i = 0; i < 2; ++i) {
            float snd = hi ? s4[i] : s4[i + 2];
            float kp  = hi ? s4[i + 2] : s4[i];
            s2[i] = kp + dxor2(snd);
        }
    }
    float S;
    {
        bool hi = (lane & 1) != 0;
        float snd = hi ? s2[0] : s2[1];
        float kp  = hi ? s2[1] : s2[0];
        S = kp + dxor1(snd);
    }
    float mr_j = (float)mj * rnorm_fast(S);
    int mrbits = __float_as_int(mr_j);

    // ---- pm[k] = v[2k]*mr0 + v[2k+1]*mr1 (packed FMA) ----
    v4f pm[8];
#define PMK(k) { \
        float mr0 = __int_as_float(SWZB(mrbits, 2*(k))); \
        float mr1 = __int_as_float(SWZB(mrbits, 2*(k)+1)); \
        pm[k] = v[2*(k)] * mr0 + v[2*(k)+1] * mr1; }
    PMK(0); PMK(1); PMK(2); PMK(3); PMK(4); PMK(5); PMK(6); PMK(7);
#undef PMK

    // ---- i2/i3/i4 via t[k] = pm[k]*pm[k+1] (packed); means cancel in l2norm ----
    v4f t[7];
#pragma unroll
    for (int k = 0; k < 7; ++k) t[k] = pm[k] * pm[k + 1];
    v4f a2 = t[0];
#pragma unroll
    for (int k = 1; k < 7; ++k) a2 += t[k];
    v4f a3 = (v4f)0.f;
#pragma unroll
    for (int k = 0; k < 6; ++k) a3 += t[k] * pm[k + 2];
    v4f a4 = (v4f)0.f;
#pragma unroll
    for (int k = 0; k < 5; ++k) a4 += t[k] * t[k + 2];

    float i2n = rnorm_fast(gred_sum16(dot4v(a2, a2))) * (1.0f / 3.0f);
    float i3n = rnorm_fast(gred_sum16(dot4v(a3, a3))) * (1.0f / 3.0f);
    float i4n = rnorm_fast(gred_sum16(dot4v(a4, a4))) * (1.0f / 3.0f);
    v4f pr = a2 * i2n + a3 * i3n + a4 * i4n;
    ((v4f*)pr_sh[p])[j] = pr;
    __syncthreads();   // bar3: qf/rf + pr_sh done

    {
        v4f q4 = ((const v4f*)qf)[j];
        v4f r4 = ((const v4f*)rf)[j];
        v4f h0 = ((const v4f*)hw)[j];
        v4f h1 = ((const v4f*)(hw + DD))[j];
        v4f wv4 = (r4 - q4) * pr * h0 + (q4 * r4) * h1;   // -(q-r) = (r-q)
        float w = gred_sum16((wv4.x + wv4.y) + (wv4.z + wv4.w));
        if (j == 0) weight_sh[p] = w;
    }
    __syncthreads();                         // bar4

    // ---- finale: wave 0 does softmax over P, pooled, scores ----
    if (wv == 0) {
        float wt = (weight_sh[lane] + hb[0]) * 5.0f;   // /0.2
        float mx = wred_max(wt);
        float e = __expf(wt - mx);
        float wn = e / wred_sum(e);
        wsh[lane] = wn;
        float pl0 = 0.f, pl1 = 0.f, pl2 = 0.f, pl3 = 0.f;
#pragma unroll 4
        for (int q = 0; q < PP; q += 4) {
            pl0 += pr_sh[q][lane] * wsh[q];
            pl1 += pr_sh[q + 1][lane] * wsh[q + 1];
            pl2 += pr_sh[q + 2][lane] * wsh[q + 2];
            pl3 += pr_sh[q + 3][lane] * wsh[q + 3];
        }
        float pooled = (pl0 + pl1) + (pl2 + pl3);
        float qv = qf[lane], rv = rf[lane];
        float sc = qv * rv * p1w[lane] + 5.0f * (rv - qv) * pooled * p2w[lane];
        float s = wred_sum(sc);
        if (lane == 0) out[b] = s + p1b[0] + 5.0f * p2b[0];
    }
}

extern "C" void kernel_launch(void* const* d_in, const int* in_sizes, int n_in,
                              void* d_out, int out_size, void* d_ws, size_t ws_size,
                              hipStream_t stream) {
    const int*   qry_id = (const int*)d_in[0];
    const int*   res_id = (const int*)d_in[1];
    const int*   path   = (const int*)d_in[2];
    const int*   mask   = (const int*)d_in[3];
    const float* img    = (const float*)d_in[4];
    const float* Ww     = (const float*)d_in[5];
    const float* Wb     = (const float*)d_in[6];
    const float* meta   = (const float*)d_in[7];
    const float* hw     = (const float*)d_in[8];
    const float* hb     = (const float*)d_in[9];
    const float* p1w    = (const float*)d_in[10];
    const float* p1b    = (const float*)d_in[11];
    const float* p2w    = (const float*)d_in[12];
    const float* p2b    = (const float*)d_in[13];

    float* out = (float*)d_out;

    hipLaunchKernelGGL(k_fused, dim3(BB), dim3(1024), 0, stream,
                       qry_id, res_id, path, mask, img, Ww, Wb, meta,
                       hw, hb, p1w, p1b, p2w, p2b, out);
}